// Round 4
// baseline (489.169 us; speedup 1.0000x reference)
//
#include <hip/hip_runtime.h>
#include <hip/hip_bf16.h>

typedef __hip_bfloat16 bf16;
typedef __hip_bfloat162 bf162;

#define B_ 8
#define N_ 1024
#define M_ 1024
#define C_ 768
#define H_ 12
#define D_ 64
#define TOUT 30
#define NT 35   // ceil(1024/30)

typedef __attribute__((ext_vector_type(8))) short short8v;
typedef __attribute__((ext_vector_type(4))) float f32x4;

__device__ __forceinline__ float bf2f(bf16 v){ return __bfloat162float(v); }
__device__ __forceinline__ bf16 f2bf(float v){ return __float2bfloat16(v); }

__device__ __forceinline__ void gl_lds16(const bf16* g, bf16* l){
  __builtin_amdgcn_global_load_lds((const __attribute__((address_space(1))) unsigned*)g,
                                   (__attribute__((address_space(3))) unsigned*)l, 16, 0, 0);
}

// ---------------- prep: fp32 -> bf16 convert (8 elems/thread) ----------------
__global__ __launch_bounds__(256)
void cvt_bf16(const float* __restrict__ in, bf16* __restrict__ out, int n8){
  int i = blockIdx.x*256 + threadIdx.x;
  if (i < n8){
    const float4* ip = reinterpret_cast<const float4*>(in) + 2*(size_t)i;
    float4 a = ip[0], b = ip[1];
    union { uint4 u; bf16 h[8]; } pk;
    pk.h[0]=f2bf(a.x); pk.h[1]=f2bf(a.y); pk.h[2]=f2bf(a.z); pk.h[3]=f2bf(a.w);
    pk.h[4]=f2bf(b.x); pk.h[5]=f2bf(b.y); pk.h[6]=f2bf(b.z); pk.h[7]=f2bf(b.w);
    reinterpret_cast<uint4*>(out)[i] = pk.u;
  }
}

// ---------------- prep: W[K][N] f32 -> Wt[N][K] bf16 ----------------
__global__ __launch_bounds__(256)
void transpose_w(const float* __restrict__ W, bf16* __restrict__ Wt, int K, int N){
  __shared__ float tile[32][33];
  const int n0 = blockIdx.x*32, k0 = blockIdx.y*32;
  const int tx = threadIdx.x & 31, ty = threadIdx.x >> 5;
#pragma unroll
  for (int i=0;i<32;i+=8) tile[ty+i][tx] = W[(size_t)(k0+ty+i)*N + n0+tx];
  __syncthreads();
#pragma unroll
  for (int i=0;i<32;i+=8) Wt[(size_t)(n0+ty+i)*K + k0+tx] = f2bf(tile[tx][ty+i]);
}

// ---- prep: Y_i[d][u] = w[3i]*V[u+1] + w[3i+1]*V[u] + w[3i+2]*V[u-1] ----
// one wave per (bh,d) row of Vt; Y1 written IN PLACE over Vt; also S_V row sums.
__global__ __launch_bounds__(256)
void yprep(bf16* __restrict__ Vt, bf16* __restrict__ Y0, bf16* __restrict__ Y2,
           float* __restrict__ SV, const float* __restrict__ conv_w)
{
  const int rowid = blockIdx.x*4 + (threadIdx.x>>6);
  const int lane = threadIdx.x & 63;
  const int bh = rowid >> 6;
  const int h = bh % H_;
  float w[9];
#pragma unroll
  for (int q=0;q<9;q++) w[q] = conv_w[h*9+q];

  const size_t off = (size_t)rowid*1024 + lane*16;
  union { uint4 u[2]; bf16 hh[16]; } ld;
  ld.u[0] = *reinterpret_cast<const uint4*>(Vt + off);
  ld.u[1] = *reinterpret_cast<const uint4*>(Vt + off + 8);
  float v[16];
#pragma unroll
  for (int e=0;e<16;e++) v[e] = bf2f(ld.hh[e]);
  float vprev = __shfl_up(v[15], 1); if (lane == 0)  vprev = 0.f;
  float vnext = __shfl_down(v[0], 1); if (lane == 63) vnext = 0.f;

  union { uint4 u[2]; bf16 hh[16]; } o0, o1, o2;
#pragma unroll
  for (int m=0;m<16;m++){
    float vm1 = (m==0)  ? vprev : v[m-1];
    float vp1 = (m==15) ? vnext : v[m+1];
    o0.hh[m] = f2bf(w[0]*vp1 + w[1]*v[m] + w[2]*vm1);
    o1.hh[m] = f2bf(w[3]*vp1 + w[4]*v[m] + w[5]*vm1);
    o2.hh[m] = f2bf(w[6]*vp1 + w[7]*v[m] + w[8]*vm1);
  }
  *reinterpret_cast<uint4*>(Y0 + off)     = o0.u[0];
  *reinterpret_cast<uint4*>(Y0 + off + 8) = o0.u[1];
  *reinterpret_cast<uint4*>(Vt + off)     = o1.u[0];
  *reinterpret_cast<uint4*>(Vt + off + 8) = o1.u[1];
  *reinterpret_cast<uint4*>(Y2 + off)     = o2.u[0];
  *reinterpret_cast<uint4*>(Y2 + off + 8) = o2.u[1];

  float s = 0.f;
#pragma unroll
  for (int e=0;e<16;e++) s += v[e];
  s += __shfl_xor(s, 1);  s += __shfl_xor(s, 2);  s += __shfl_xor(s, 4);
  s += __shfl_xor(s, 8);  s += __shfl_xor(s, 16); s += __shfl_xor(s, 32);
  if (lane == 0) SV[rowid] = s;
}

// ---------------- bf16 MFMA GEMM: A[8192][K] @ Bt[N][K]^T ----------------
__global__ __launch_bounds__(256)
void gemm_bf16(const bf16* __restrict__ A, const bf16* __restrict__ Bt, int K,
               int nbx, const float* __restrict__ bias,
               float* __restrict__ outf, bf16* __restrict__ outQ,
               bf16* __restrict__ outK, bf16* __restrict__ outV, int mode)
{
  __shared__ bf16 As[128*32];
  __shared__ bf16 Bs[128*32];

  const int nwg = 64*nbx, cpx = nwg >> 3;
  int bid = blockIdx.x;
  bid = (bid & 7)*cpx + (bid >> 3);
  const int rowb = bid / nbx, colb = bid - rowb*nbx;
  const int row0 = rowb*128, c0 = colb*128;

  const int t = threadIdx.x;
  const int w = t>>6, l = t&63, lr = l&15, g = l>>4;
  const int wr = w>>1, wc = w&1;

  const bf16* Ap = A + (size_t)row0*K;
  const bf16* Bp = Bt + (size_t)c0*K;
  const int srow = t>>2;
  const int schunk = (t&3)*8;

  f32x4 acc[4][4];
#pragma unroll
  for (int mi=0;mi<4;mi++)
#pragma unroll
    for (int ni=0;ni<4;ni++) acc[mi][ni] = (f32x4){0.f,0.f,0.f,0.f};

  for (int k0 = 0; k0 < K; k0 += 32){
    gl_lds16(Ap + (size_t)srow*K      + k0 + schunk, As + t*8);
    gl_lds16(Ap + (size_t)(srow+64)*K + k0 + schunk, As + 2048 + t*8);
    gl_lds16(Bp + (size_t)srow*K      + k0 + schunk, Bs + t*8);
    gl_lds16(Bp + (size_t)(srow+64)*K + k0 + schunk, Bs + 2048 + t*8);
    __syncthreads();

    short8v a[4], b[4];
#pragma unroll
    for (int mi=0;mi<4;mi++)
      a[mi] = *reinterpret_cast<const short8v*>(&As[(wr*64+mi*16+lr)*32 + g*8]);
#pragma unroll
    for (int ni=0;ni<4;ni++)
      b[ni] = *reinterpret_cast<const short8v*>(&Bs[(wc*64+ni*16+lr)*32 + g*8]);
#pragma unroll
    for (int mi=0;mi<4;mi++)
#pragma unroll
      for (int ni=0;ni<4;ni++)
        acc[mi][ni] = __builtin_amdgcn_mfma_f32_16x16x32_bf16(a[mi], b[ni], acc[mi][ni], 0,0,0);
    __syncthreads();
  }

  if (mode == 2){
    float bv[4];
#pragma unroll
    for (int ni=0;ni<4;ni++) bv[ni] = bias[c0 + wc*64 + ni*16 + lr];
#pragma unroll
    for (int mi=0;mi<4;mi++)
#pragma unroll
      for (int ni=0;ni<4;ni++){
        int c = c0 + wc*64 + ni*16 + lr;
#pragma unroll
        for (int q=0;q<4;q++){
          int grow = row0 + wr*64 + mi*16 + g*4 + q;
          outf[(size_t)grow*C_ + c] = acc[mi][ni][q] + bv[ni];
        }
      }
  } else if (mode == 0){
#pragma unroll
    for (int mi=0;mi<4;mi++)
#pragma unroll
      for (int ni=0;ni<4;ni++){
        int c = c0 + wc*64 + ni*16 + lr;
        int h = c >> 6, dd = c & 63;
#pragma unroll
        for (int q=0;q<4;q++){
          int grow = row0 + wr*64 + mi*16 + g*4 + q;
          int b = grow >> 10, n = grow & 1023;
          outQ[((((size_t)b*H_ + h)*N_ + n)<<6) + dd] = f2bf(acc[mi][ni][q]);
        }
      }
  } else {
#pragma unroll
    for (int mi=0;mi<4;mi++)
#pragma unroll
      for (int ni=0;ni<4;ni++){
        int c = c0 + wc*64 + ni*16 + lr;
        if (c < 768){
          int h = c >> 6, dd = c & 63;
#pragma unroll
          for (int q=0;q<4;q++){
            int grow = row0 + wr*64 + mi*16 + g*4 + q;
            int b = grow >> 10, m = grow & 1023;
            outK[((((size_t)b*H_ + h)*M_ + m)<<6) + dd] = f2bf(acc[mi][ni][q]);
          }
        } else {
          int cc = c - 768;
          int h = cc >> 6, dd = cc & 63;
          int grow = row0 + wr*64 + mi*16 + g*4;
          int b = grow >> 10, m = grow & 1023;
          union { ushort4 u; bf16 hh[4]; } pk;
#pragma unroll
          for (int q=0;q<4;q++) pk.hh[q] = f2bf(acc[mi][ni][q]);
          size_t off = (((size_t)b*H_ + h)*D_ + dd)*(size_t)M_ + m;
          *reinterpret_cast<ushort4*>(&outV[off]) = pk.u;
        }
      }
  }
}

// -------- fused attention: MFMA scores -> reg softmax -> 3x(P@Y_i) -> combine
__global__ __launch_bounds__(512, 4)
void attn_fused(const bf16* __restrict__ Qb, const bf16* __restrict__ Kb,
                const bf16* __restrict__ Y0, const bf16* __restrict__ Y1,
                const bf16* __restrict__ Y2, const float* __restrict__ SV,
                const float* __restrict__ conv_b, bf16* __restrict__ midb)
{
  __shared__ char smraw[65536];      // P[32][1024] bf16 (m-swizzled)  /  U[3][32][68] f32
  __shared__ float red[2][8][32];
  bf16*  smP = reinterpret_cast<bf16*>(smraw);
  float* smU = reinterpret_cast<float*>(smraw);

  const int t = threadIdx.x;
  const int w = t >> 6, l = t & 63;
  const int lr = l & 15, g = l >> 4;

  int L = blockIdx.x + blockIdx.y * NT;
  int L2 = (L & 7) * 420 + (L >> 3);
  const int bh = L2 / NT;
  const int tile = L2 - bh * NT;
  const int b = bh / H_, h = bh - b*H_;
  const int n0 = tile * TOUT;

  const bf16* Qp = Qb + (size_t)bh * (N_*D_);
  const bf16* Kp = Kb + (size_t)bh * (M_*D_);
  const size_t ybase = (size_t)bh * (D_*M_);
  const float cbv = conv_b[h];

  // ---- Q fragments, halo rows zeroed ----
  short8v qf[2][2];
#pragma unroll
  for (int rt=0;rt<2;rt++){
    int n = n0 - 1 + rt*16 + lr;
    bool ok = (unsigned)n < (unsigned)N_;
#pragma unroll
    for (int kk=0;kk<2;kk++){
      if (ok) qf[rt][kk] = *reinterpret_cast<const short8v*>(Qp + (size_t)n*D_ + kk*32 + g*8);
      else    qf[rt][kk] = short8v{0,0,0,0,0,0,0,0};
    }
  }

  // ---- scores S[32][1024] via MFMA; wave w owns cols (8i+w)*16 ----
  f32x4 acc[8][2];
#pragma unroll
  for (int i=0;i<8;i++)
#pragma unroll
    for (int rt=0;rt<2;rt++)
      acc[i][rt] = (f32x4){0.f,0.f,0.f,0.f};

#pragma unroll
  for (int i=0;i<8;i++){
    const int m0 = (i*8 + w)*16;
    const bf16* kp = Kp + (size_t)(m0 + lr)*D_ + g*8;
    short8v kf0 = *reinterpret_cast<const short8v*>(kp);
    short8v kf1 = *reinterpret_cast<const short8v*>(kp + 32);
    acc[i][0] = __builtin_amdgcn_mfma_f32_16x16x32_bf16(qf[0][0], kf0, acc[i][0], 0,0,0);
    acc[i][1] = __builtin_amdgcn_mfma_f32_16x16x32_bf16(qf[1][0], kf0, acc[i][1], 0,0,0);
    acc[i][0] = __builtin_amdgcn_mfma_f32_16x16x32_bf16(qf[0][1], kf1, acc[i][0], 0,0,0);
    acc[i][1] = __builtin_amdgcn_mfma_f32_16x16x32_bf16(qf[1][1], kf1, acc[i][1], 0,0,0);
  }

  // ---- softmax (row = rt*16 + g*4 + q) ----
  const float scale = 0.125f;
  float rmax[2][4], rsum[2][4];

#pragma unroll
  for (int rt=0;rt<2;rt++)
#pragma unroll
    for (int q=0;q<4;q++){
      float m = -1e30f;
#pragma unroll
      for (int i=0;i<8;i++) m = fmaxf(m, acc[i][rt][q]);
      m = fmaxf(m, __shfl_xor(m, 1));
      m = fmaxf(m, __shfl_xor(m, 2));
      m = fmaxf(m, __shfl_xor(m, 4));
      m = fmaxf(m, __shfl_xor(m, 8));
      rmax[rt][q] = m;
    }
  if (lr == 0){
#pragma unroll
    for (int rt=0;rt<2;rt++)
#pragma unroll
      for (int q=0;q<4;q++) red[0][w][rt*16+g*4+q] = rmax[rt][q];
  }
  __syncthreads();
#pragma unroll
  for (int rt=0;rt<2;rt++)
#pragma unroll
    for (int q=0;q<4;q++){
      int r = rt*16+g*4+q;
      float m = red[0][0][r];
#pragma unroll
      for (int ww=1;ww<8;ww++) m = fmaxf(m, red[0][ww][r]);
      rmax[rt][q] = m;
    }

#pragma unroll
  for (int rt=0;rt<2;rt++)
#pragma unroll
    for (int q=0;q<4;q++){
      float s = 0.f;
#pragma unroll
      for (int i=0;i<8;i++){
        float p = __expf((acc[i][rt][q] - rmax[rt][q]) * scale);
        acc[i][rt][q] = p;
        s += p;
      }
      s += __shfl_xor(s, 1);
      s += __shfl_xor(s, 2);
      s += __shfl_xor(s, 4);
      s += __shfl_xor(s, 8);
      rsum[rt][q] = s;
    }
  if (lr == 0){
#pragma unroll
    for (int rt=0;rt<2;rt++)
#pragma unroll
      for (int q=0;q<4;q++) red[1][w][rt*16+g*4+q] = rsum[rt][q];
  }
  __syncthreads();

  float rinv[2][4];
#pragma unroll
  for (int rt=0;rt<2;rt++)
#pragma unroll
    for (int q=0;q<4;q++){
      int r = rt*16+g*4+q;
      float s = red[1][0][r];
#pragma unroll
      for (int ww=1;ww<8;ww++) s += red[1][ww][r];
      int n = n0 - 1 + r;
      rinv[rt][q] = ((unsigned)n < (unsigned)N_) ? (1.0f / s) : 0.f;
    }

  // ---- write normalized P row-major (T2 XOR-swizzled) ----
#pragma unroll
  for (int i=0;i<8;i++){
    const int m = (i*8 + w)*16 + lr;
#pragma unroll
    for (int rt=0;rt<2;rt++)
#pragma unroll
      for (int q=0;q<4;q++){
        int r = rt*16 + g*4 + q;
        smP[r*1024 + (m ^ ((r & 7) << 3))] = f2bf(acc[i][rt][q] * rinv[rt][q]);
      }
  }
  __syncthreads();

  // ---- PV x3: U_i = P @ Y_i ----
  const int rtw = w >> 2, ctw = w & 3;
  const int arow = rtw*16 + lr;
  const size_t bcol = ybase + (size_t)(ctw*16 + lr)*M_;
  f32x4 U0 = (f32x4){0.f,0.f,0.f,0.f};
  f32x4 U1 = (f32x4){0.f,0.f,0.f,0.f};
  f32x4 U2 = (f32x4){0.f,0.f,0.f,0.f};

  for (int mc = 0; mc < M_; mc += 128){
#pragma unroll
    for (int ks=0; ks<4; ks++){
      const int ke = mc + ks*32 + g*8;
      short8v a = *reinterpret_cast<const short8v*>(
          &smP[arow*1024 + (ke ^ ((arow & 7) << 3))]);
      short8v b0 = *reinterpret_cast<const short8v*>(Y0 + bcol + ke);
      short8v b1 = *reinterpret_cast<const short8v*>(Y1 + bcol + ke);
      short8v b2 = *reinterpret_cast<const short8v*>(Y2 + bcol + ke);
      U0 = __builtin_amdgcn_mfma_f32_16x16x32_bf16(a, b0, U0, 0,0,0);
      U1 = __builtin_amdgcn_mfma_f32_16x16x32_bf16(a, b1, U1, 0,0,0);
      U2 = __builtin_amdgcn_mfma_f32_16x16x32_bf16(a, b2, U2, 0,0,0);
    }
  }
  __syncthreads();   // all waves done reading P

  // ---- stage U to LDS (stride 68 kills write conflicts) ----
#pragma unroll
  for (int q=0;q<4;q++){
    int r = rtw*16 + g*4 + q;
    smU[(0*32 + r)*68 + ctw*16 + lr] = U0[q];
    smU[(1*32 + r)*68 + ctw*16 + lr] = U1[q];
    smU[(2*32 + r)*68 + ctw*16 + lr] = U2[q];
  }
  __syncthreads();

  // ---- combine: O[r] = cb*S_V + U0[r-1] + U1[r] + U2[r+1] ----
  {
    const int r = t >> 4;
    const int d0 = (t & 15) * 4;
    if (r >= 1 && r <= 30){
      int n = n0 - 1 + r;
      if (n < N_){
        const float4 sv = *reinterpret_cast<const float4*>(&SV[bh*64 + d0]);
        union { ushort4 u; bf16 hh[4]; } pk;
        float o0 = cbv*sv.x + smU[(r-1)*68 + d0+0] + smU[(32+r)*68 + d0+0] + smU[(64+r+1)*68 + d0+0];
        float o1 = cbv*sv.y + smU[(r-1)*68 + d0+1] + smU[(32+r)*68 + d0+1] + smU[(64+r+1)*68 + d0+1];
        float o2 = cbv*sv.z + smU[(r-1)*68 + d0+2] + smU[(32+r)*68 + d0+2] + smU[(64+r+1)*68 + d0+2];
        float o3 = cbv*sv.w + smU[(r-1)*68 + d0+3] + smU[(32+r)*68 + d0+3] + smU[(64+r+1)*68 + d0+3];
        pk.hh[0]=f2bf(o0); pk.hh[1]=f2bf(o1); pk.hh[2]=f2bf(o2); pk.hh[3]=f2bf(o3);
        *reinterpret_cast<ushort4*>(&midb[((size_t)b*N_ + n)*C_ + h*D_ + d0]) = pk.u;
      }
    }
  }
}

extern "C" void kernel_launch(void* const* d_in, const int* in_sizes, int n_in,
                              void* d_out, int out_size, void* d_ws, size_t ws_size,
                              hipStream_t stream) {
  const float* x     = (const float*)d_in[0];
  const float* ctx   = (const float*)d_in[1];
  const float* Wq    = (const float*)d_in[2];
  const float* Wkv   = (const float*)d_in[3];
  const float* convw = (const float*)d_in[4];
  const float* convb = (const float*)d_in[5];
  const float* Wp    = (const float*)d_in[6];
  const float* bp    = (const float*)d_in[7];
  float* out = (float*)d_out;

  char* ws = (char*)d_ws;
  bf16* buf0 = (bf16*)(ws);                  // 12582912 B (xb -> ctxb -> midb)
  bf16* Wqt  = (bf16*)(ws + 12582912);       // 1179648
  bf16* Wkvt = (bf16*)(ws + 13762560);       // 2359296
  bf16* Wpt  = (bf16*)(ws + 16121856);       // 1179648
  bf16* Qb   = (bf16*)(ws + 17301504);       // 12582912
  bf16* Kb   = (bf16*)(ws + 29884416);       // 12582912
  bf16* Vt   = (bf16*)(ws + 42467328);       // 12582912 (becomes Y1 in place)
  float* SVb = (float*)(ws + 55050240);      // 24576   -> end 55074816

  // Y0/Y2 scratch lives in d_out (25.2 MB), fully overwritten by final GEMM
  bf16* Y0 = (bf16*)d_out;
  bf16* Y2 = (bf16*)((char*)d_out + 12582912);

  transpose_w<<<dim3(24,24), 256, 0, stream>>>(Wq,  Wqt,  768, 768);
  transpose_w<<<dim3(48,24), 256, 0, stream>>>(Wkv, Wkvt, 768, 1536);
  transpose_w<<<dim3(24,24), 256, 0, stream>>>(Wp,  Wpt,  768, 768);

  cvt_bf16<<<3072, 256, 0, stream>>>(x, buf0, 786432);
  gemm_bf16<<<384, 256, 0, stream>>>(buf0, Wqt, 768, 6, nullptr, nullptr, Qb, nullptr, nullptr, 0);
  cvt_bf16<<<3072, 256, 0, stream>>>(ctx, buf0, 786432);
  gemm_bf16<<<768, 256, 0, stream>>>(buf0, Wkvt, 768, 12, nullptr, nullptr, nullptr, Kb, Vt, 1);

  yprep<<<1536, 256, 0, stream>>>(Vt, Y0, Y2, SVb, convw);

  attn_fused<<<dim3(NT,96), dim3(512), 0, stream>>>(Qb, Kb, Y0, Vt, Y2, SVb, convb, buf0);

  gemm_bf16<<<384, 256, 0, stream>>>(buf0, Wpt, 768, 6, bp, out, nullptr, nullptr, nullptr, 2);
}

// Round 6
// 345.312 us; speedup vs baseline: 1.4166x; 1.4166x over previous
//
#include <hip/hip_runtime.h>
#include <hip/hip_bf16.h>

typedef __hip_bfloat16 bf16;
typedef __hip_bfloat162 bf162;

#define B_ 8
#define N_ 1024
#define M_ 1024
#define C_ 768
#define H_ 12
#define D_ 64
#define TOUT 30
#define NT 35   // ceil(1024/30)

typedef __attribute__((ext_vector_type(8))) short short8v;
typedef __attribute__((ext_vector_type(4))) float f32x4;

__device__ __forceinline__ float bf2f(bf16 v){ return __bfloat162float(v); }
__device__ __forceinline__ bf16 f2bf(float v){ return __float2bfloat16(v); }

__device__ __forceinline__ void gl_lds16(const bf16* g, bf16* l){
  __builtin_amdgcn_global_load_lds((const __attribute__((address_space(1))) unsigned*)g,
                                   (__attribute__((address_space(3))) unsigned*)l, 16, 0, 0);
}

// ---------------- prep: fp32 -> bf16 convert (8 elems/thread) ----------------
__global__ __launch_bounds__(256)
void cvt_bf16(const float* __restrict__ in, bf16* __restrict__ out, int n8){
  int i = blockIdx.x*256 + threadIdx.x;
  if (i < n8){
    const float4* ip = reinterpret_cast<const float4*>(in) + 2*(size_t)i;
    float4 a = ip[0], b = ip[1];
    union { uint4 u; bf16 h[8]; } pk;
    pk.h[0]=f2bf(a.x); pk.h[1]=f2bf(a.y); pk.h[2]=f2bf(a.z); pk.h[3]=f2bf(a.w);
    pk.h[4]=f2bf(b.x); pk.h[5]=f2bf(b.y); pk.h[6]=f2bf(b.z); pk.h[7]=f2bf(b.w);
    reinterpret_cast<uint4*>(out)[i] = pk.u;
  }
}

// ---------------- prep: W[K][N] f32 -> Wt[N][K] bf16 ----------------
__global__ __launch_bounds__(256)
void transpose_w(const float* __restrict__ W, bf16* __restrict__ Wt, int K, int N){
  __shared__ float tile[32][33];
  const int n0 = blockIdx.x*32, k0 = blockIdx.y*32;
  const int tx = threadIdx.x & 31, ty = threadIdx.x >> 5;
#pragma unroll
  for (int i=0;i<32;i+=8) tile[ty+i][tx] = W[(size_t)(k0+ty+i)*N + n0+tx];
  __syncthreads();
#pragma unroll
  for (int i=0;i<32;i+=8) Wt[(size_t)(n0+ty+i)*K + k0+tx] = f2bf(tile[tx][ty+i]);
}

// ---- prep v3: per-(b,h) panel. Reads Vt[bh][d][m] row-major; emits
// Y_i[d][u] = w[3i]*V[u+1] + w[3i+1]*V[u] + w[3i+2]*V[u-1]  (u along m)
// in PV-frag-tiled layout: eidx = (m>>5)*2048 + d*32 + (m&31).
// Y2 written IN PLACE over the Vt slot (panel fully LDS-staged first). Also SV.
__global__ __launch_bounds__(1024)
void yprep(bf16* __restrict__ Vt, bf16* __restrict__ Y0, bf16* __restrict__ Y1,
           float* __restrict__ SV, const float* __restrict__ conv_w)
{
  __shared__ bf16 sm[65536];          // V panel [64][1024], 128 KB
  const int t = threadIdx.x;
  const int bh = blockIdx.x;
  const int h = bh % H_;
  const size_t pbase = (size_t)bh * 65536;

  float w[9];
#pragma unroll
  for (int q=0;q<9;q++) w[q] = conv_w[h*9+q];

  // stage full panel, coalesced: 8 iters x (1024 thr x 16B contiguous)
#pragma unroll
  for (int k=0;k<8;k++){
    int idx = k*8192 + t*8;
    *reinterpret_cast<uint4*>(&sm[idx]) = *reinterpret_cast<const uint4*>(Vt + pbase + idx);
  }
  __syncthreads();

  // thread t owns d = t>>4, m-segment j*64..j*64+63 (j = t&15)
  const int d = t >> 4;
  const int j = t & 15;
  float ssum = 0.f;
#pragma unroll
  for (int k=0;k<8;k++){
    const int moff = j*64 + k*8;
    const int base = d*1024 + moff;
    union { uint4 u; bf16 hh[8]; } mv;
    mv.u = *reinterpret_cast<const uint4*>(&sm[base]);
    float v[8];
#pragma unroll
    for (int e=0;e<8;e++) v[e] = bf2f(mv.hh[e]);
    float vl = (moff == 0)    ? 0.f : bf2f(sm[base-1]);
    float vr = (moff == 1016) ? 0.f : bf2f(sm[base+8]);

    union { uint4 u; bf16 hh[8]; } o0, o1, o2;
#pragma unroll
    for (int m=0;m<8;m++){
      float vm1 = (m==0) ? vl : v[m-1];
      float vp1 = (m==7) ? vr : v[m+1];
      o0.hh[m] = f2bf(w[0]*vp1 + w[1]*v[m] + w[2]*vm1);
      o1.hh[m] = f2bf(w[3]*vp1 + w[4]*v[m] + w[5]*vm1);
      o2.hh[m] = f2bf(w[6]*vp1 + w[7]*v[m] + w[8]*vm1);
      ssum += v[m];
    }
    size_t go = pbase + ((size_t)(moff>>5)<<11) + d*32 + (moff&31);
    *reinterpret_cast<uint4*>(Y0 + go) = o0.u;
    *reinterpret_cast<uint4*>(Y1 + go) = o1.u;
    *reinterpret_cast<uint4*>(Vt + go) = o2.u;   // Y2 in place
  }

  // SV[bh*64+d] = sum over m of V[m][d]; 16 threads (j=0..15) cover the row
  ssum += __shfl_xor(ssum, 1);
  ssum += __shfl_xor(ssum, 2);
  ssum += __shfl_xor(ssum, 4);
  ssum += __shfl_xor(ssum, 8);
  if (j == 0) SV[bh*64 + d] = ssum;
}

// ---------------- bf16 MFMA GEMM: A[8192][K] @ Bt[N][K]^T ----------------
// mode 0: out -> Qb[b,h,n,d] bf16
// mode 1: cols<768 -> Kb tiled frag-major; cols>=768 -> Vt[b,h,d,m]
// mode 2: +bias -> outf fp32
__global__ __launch_bounds__(256)
void gemm_bf16(const bf16* __restrict__ A, const bf16* __restrict__ Bt, int K,
               int nbx, const float* __restrict__ bias,
               float* __restrict__ outf, bf16* __restrict__ outQ,
               bf16* __restrict__ outK, bf16* __restrict__ outV, int mode)
{
  __shared__ bf16 As[128*32];
  __shared__ bf16 Bs[128*32];

  const int nwg = 64*nbx, cpx = nwg >> 3;
  int bid = blockIdx.x;
  bid = (bid & 7)*cpx + (bid >> 3);
  const int rowb = bid / nbx, colb = bid - rowb*nbx;
  const int row0 = rowb*128, c0 = colb*128;

  const int t = threadIdx.x;
  const int w = t>>6, l = t&63, lr = l&15, g = l>>4;
  const int wr = w>>1, wc = w&1;

  const bf16* Ap = A + (size_t)row0*K;
  const bf16* Bp = Bt + (size_t)c0*K;
  const int srow = t>>2;
  const int schunk = (t&3)*8;

  f32x4 acc[4][4];
#pragma unroll
  for (int mi=0;mi<4;mi++)
#pragma unroll
    for (int ni=0;ni<4;ni++) acc[mi][ni] = (f32x4){0.f,0.f,0.f,0.f};

  for (int k0 = 0; k0 < K; k0 += 32){
    gl_lds16(Ap + (size_t)srow*K      + k0 + schunk, As + t*8);
    gl_lds16(Ap + (size_t)(srow+64)*K + k0 + schunk, As + 2048 + t*8);
    gl_lds16(Bp + (size_t)srow*K      + k0 + schunk, Bs + t*8);
    gl_lds16(Bp + (size_t)(srow+64)*K + k0 + schunk, Bs + 2048 + t*8);
    __syncthreads();

    short8v a[4], b[4];
#pragma unroll
    for (int mi=0;mi<4;mi++)
      a[mi] = *reinterpret_cast<const short8v*>(&As[(wr*64+mi*16+lr)*32 + g*8]);
#pragma unroll
    for (int ni=0;ni<4;ni++)
      b[ni] = *reinterpret_cast<const short8v*>(&Bs[(wc*64+ni*16+lr)*32 + g*8]);
#pragma unroll
    for (int mi=0;mi<4;mi++)
#pragma unroll
      for (int ni=0;ni<4;ni++)
        acc[mi][ni] = __builtin_amdgcn_mfma_f32_16x16x32_bf16(a[mi], b[ni], acc[mi][ni], 0,0,0);
    __syncthreads();
  }

  if (mode == 2){
    float bv[4];
#pragma unroll
    for (int ni=0;ni<4;ni++) bv[ni] = bias[c0 + wc*64 + ni*16 + lr];
#pragma unroll
    for (int mi=0;mi<4;mi++)
#pragma unroll
      for (int ni=0;ni<4;ni++){
        int c = c0 + wc*64 + ni*16 + lr;
#pragma unroll
        for (int q=0;q<4;q++){
          int grow = row0 + wr*64 + mi*16 + g*4 + q;
          outf[(size_t)grow*C_ + c] = acc[mi][ni][q] + bv[ni];
        }
      }
  } else if (mode == 0){
#pragma unroll
    for (int mi=0;mi<4;mi++)
#pragma unroll
      for (int ni=0;ni<4;ni++){
        int c = c0 + wc*64 + ni*16 + lr;
        int h = c >> 6, dd = c & 63;
#pragma unroll
        for (int q=0;q<4;q++){
          int grow = row0 + wr*64 + mi*16 + g*4 + q;
          int b = grow >> 10, n = grow & 1023;
          outQ[((((size_t)b*H_ + h)*N_ + n)<<6) + dd] = f2bf(acc[mi][ni][q]);
        }
      }
  } else {
#pragma unroll
    for (int mi=0;mi<4;mi++)
#pragma unroll
      for (int ni=0;ni<4;ni++){
        int c = c0 + wc*64 + ni*16 + lr;
        if (c < 768){
          int h = c >> 6, dd = c & 63;
#pragma unroll
          for (int q=0;q<4;q++){
            int grow = row0 + wr*64 + mi*16 + g*4 + q;
            int b = grow >> 10, m = grow & 1023;
            // frag-major tiled K: eidx = (m/16)*1024 + (d/8)*128 + (m%16)*8 + d%8
            int eidx = ((m>>4)<<10) + ((dd>>3)<<7) + ((m&15)<<3) + (dd&7);
            outK[((size_t)b*H_ + h)*65536 + eidx] = f2bf(acc[mi][ni][q]);
          }
        } else {
          int cc = c - 768;
          int h = cc >> 6, dd = cc & 63;
          int grow = row0 + wr*64 + mi*16 + g*4;
          int b = grow >> 10, m = grow & 1023;
          union { ushort4 u; bf16 hh[4]; } pk;
#pragma unroll
          for (int q=0;q<4;q++) pk.hh[q] = f2bf(acc[mi][ni][q]);
          size_t off = (((size_t)b*H_ + h)*D_ + dd)*(size_t)M_ + m;
          *reinterpret_cast<ushort4*>(&outV[off]) = pk.u;
        }
      }
  }
}

// -------- fused attention: MFMA scores -> reg softmax -> 3x(P@Y_i) -> combine
__global__ __launch_bounds__(512, 4)
void attn_fused(const bf16* __restrict__ Qb, const bf16* __restrict__ Kb,
                const bf16* __restrict__ Y0, const bf16* __restrict__ Y1,
                const bf16* __restrict__ Y2, const float* __restrict__ SV,
                const float* __restrict__ conv_b, bf16* __restrict__ midb)
{
  __shared__ char smraw[65536];      // P[32][1024] bf16 (m-swizzled)  /  U[3][32][68] f32
  __shared__ float red[2][8][32];
  bf16*  smP = reinterpret_cast<bf16*>(smraw);
  float* smU = reinterpret_cast<float*>(smraw);

  const int t = threadIdx.x;
  const int w = t >> 6, l = t & 63;
  const int lr = l & 15, g = l >> 4;

  int L = blockIdx.x + blockIdx.y * NT;
  int L2 = (L & 7) * 420 + (L >> 3);
  const int bh = L2 / NT;
  const int tile = L2 - bh * NT;
  const int b = bh / H_, h = bh - b*H_;
  const int n0 = tile * TOUT;

  const bf16* Qp = Qb + (size_t)bh * (N_*D_);
  const bf16* Kp = Kb + (size_t)bh * 65536;   // tiled
  const size_t ybase = (size_t)bh * 65536;    // tiled
  const float cbv = conv_b[h];

  // ---- Q fragments, halo rows zeroed ----
  short8v qf[2][2];
#pragma unroll
  for (int rt=0;rt<2;rt++){
    int n = n0 - 1 + rt*16 + lr;
    bool ok = (unsigned)n < (unsigned)N_;
#pragma unroll
    for (int kk=0;kk<2;kk++){
      if (ok) qf[rt][kk] = *reinterpret_cast<const short8v*>(Qp + (size_t)n*D_ + kk*32 + g*8);
      else    qf[rt][kk] = short8v{0,0,0,0,0,0,0,0};
    }
  }

  // ---- scores S[32][1024] via MFMA; wave w owns cols (8i+w)*16 ----
  f32x4 acc[8][2];
#pragma unroll
  for (int i=0;i<8;i++)
#pragma unroll
    for (int rt=0;rt<2;rt++)
      acc[i][rt] = (f32x4){0.f,0.f,0.f,0.f};

#pragma unroll
  for (int i=0;i<8;i++){
    // tiled K: contiguous 1KB per wave-load
    const bf16* kp = Kp + (((size_t)(i*8 + w))<<10) + (g<<7) + (lr<<3);
    short8v kf0 = *reinterpret_cast<const short8v*>(kp);
    short8v kf1 = *reinterpret_cast<const short8v*>(kp + 512);
    acc[i][0] = __builtin_amdgcn_mfma_f32_16x16x32_bf16(qf[0][0], kf0, acc[i][0], 0,0,0);
    acc[i][1] = __builtin_amdgcn_mfma_f32_16x16x32_bf16(qf[1][0], kf0, acc[i][1], 0,0,0);
    acc[i][0] = __builtin_amdgcn_mfma_f32_16x16x32_bf16(qf[0][1], kf1, acc[i][0], 0,0,0);
    acc[i][1] = __builtin_amdgcn_mfma_f32_16x16x32_bf16(qf[1][1], kf1, acc[i][1], 0,0,0);
  }

  // ---- softmax (row = rt*16 + g*4 + q) ----
  const float scale = 0.125f;
  float rmax[2][4], rsum[2][4];

#pragma unroll
  for (int rt=0;rt<2;rt++)
#pragma unroll
    for (int q=0;q<4;q++){
      float m = -1e30f;
#pragma unroll
      for (int i=0;i<8;i++) m = fmaxf(m, acc[i][rt][q]);
      m = fmaxf(m, __shfl_xor(m, 1));
      m = fmaxf(m, __shfl_xor(m, 2));
      m = fmaxf(m, __shfl_xor(m, 4));
      m = fmaxf(m, __shfl_xor(m, 8));
      rmax[rt][q] = m;
    }
  if (lr == 0){
#pragma unroll
    for (int rt=0;rt<2;rt++)
#pragma unroll
      for (int q=0;q<4;q++) red[0][w][rt*16+g*4+q] = rmax[rt][q];
  }
  __syncthreads();
#pragma unroll
  for (int rt=0;rt<2;rt++)
#pragma unroll
    for (int q=0;q<4;q++){
      int r = rt*16+g*4+q;
      float m = red[0][0][r];
#pragma unroll
      for (int ww=1;ww<8;ww++) m = fmaxf(m, red[0][ww][r]);
      rmax[rt][q] = m;
    }

#pragma unroll
  for (int rt=0;rt<2;rt++)
#pragma unroll
    for (int q=0;q<4;q++){
      float s = 0.f;
#pragma unroll
      for (int i=0;i<8;i++){
        float p = __expf((acc[i][rt][q] - rmax[rt][q]) * scale);
        acc[i][rt][q] = p;
        s += p;
      }
      s += __shfl_xor(s, 1);
      s += __shfl_xor(s, 2);
      s += __shfl_xor(s, 4);
      s += __shfl_xor(s, 8);
      rsum[rt][q] = s;
    }
  if (lr == 0){
#pragma unroll
    for (int rt=0;rt<2;rt++)
#pragma unroll
      for (int q=0;q<4;q++) red[1][w][rt*16+g*4+q] = rsum[rt][q];
  }
  __syncthreads();

  float rinv[2][4];
#pragma unroll
  for (int rt=0;rt<2;rt++)
#pragma unroll
    for (int q=0;q<4;q++){
      int r = rt*16+g*4+q;
      float s = red[1][0][r];
#pragma unroll
      for (int ww=1;ww<8;ww++) s += red[1][ww][r];
      int n = n0 - 1 + r;
      rinv[rt][q] = ((unsigned)n < (unsigned)N_) ? (1.0f / s) : 0.f;
    }

  // ---- write normalized P row-major (T2 XOR-swizzled) ----
#pragma unroll
  for (int i=0;i<8;i++){
    const int m = (i*8 + w)*16 + lr;
#pragma unroll
    for (int rt=0;rt<2;rt++)
#pragma unroll
      for (int q=0;q<4;q++){
        int r = rt*16 + g*4 + q;
        smP[r*1024 + (m ^ ((r & 7) << 3))] = f2bf(acc[i][rt][q] * rinv[rt][q]);
      }
  }
  __syncthreads();

  // ---- PV x3: U_i = P @ Y_i (tiled Y: coalesced B-frags) ----
  const int rtw = w >> 2, ctw = w & 3;
  const int arow = rtw*16 + lr;
  const int dcol = ctw*16 + lr;
  f32x4 U0 = (f32x4){0.f,0.f,0.f,0.f};
  f32x4 U1 = (f32x4){0.f,0.f,0.f,0.f};
  f32x4 U2 = (f32x4){0.f,0.f,0.f,0.f};

  for (int mc = 0; mc < M_; mc += 128){
#pragma unroll
    for (int ks=0; ks<4; ks++){
      const int ke = mc + ks*32 + g*8;
      short8v a = *reinterpret_cast<const short8v*>(
          &smP[arow*1024 + (ke ^ ((arow & 7) << 3))]);
      const size_t eoff = ybase + ((size_t)((mc>>5)+ks)<<11) + dcol*32 + g*8;
      short8v b0 = *reinterpret_cast<const short8v*>(Y0 + eoff);
      short8v b1 = *reinterpret_cast<const short8v*>(Y1 + eoff);
      short8v b2 = *reinterpret_cast<const short8v*>(Y2 + eoff);
      U0 = __builtin_amdgcn_mfma_f32_16x16x32_bf16(a, b0, U0, 0,0,0);
      U1 = __builtin_amdgcn_mfma_f32_16x16x32_bf16(a, b1, U1, 0,0,0);
      U2 = __builtin_amdgcn_mfma_f32_16x16x32_bf16(a, b2, U2, 0,0,0);
    }
  }
  __syncthreads();   // all waves done reading P

  // ---- stage U to LDS (stride 68 kills write conflicts) ----
#pragma unroll
  for (int q=0;q<4;q++){
    int r = rtw*16 + g*4 + q;
    smU[(0*32 + r)*68 + dcol] = U0[q];
    smU[(1*32 + r)*68 + dcol] = U1[q];
    smU[(2*32 + r)*68 + dcol] = U2[q];
  }
  __syncthreads();

  // ---- combine: O[r] = cb*S_V + U0[r-1] + U1[r] + U2[r+1] ----
  {
    const int r = t >> 4;
    const int d0 = (t & 15) * 4;
    if (r >= 1 && r <= 30){
      int n = n0 - 1 + r;
      if (n < N_){
        const float4 sv = *reinterpret_cast<const float4*>(&SV[bh*64 + d0]);
        union { ushort4 u; bf16 hh[4]; } pk;
        float o0 = cbv*sv.x + smU[(r-1)*68 + d0+0] + smU[(32+r)*68 + d0+0] + smU[(64+r+1)*68 + d0+0];
        float o1 = cbv*sv.y + smU[(r-1)*68 + d0+1] + smU[(32+r)*68 + d0+1] + smU[(64+r+1)*68 + d0+1];
        float o2 = cbv*sv.z + smU[(r-1)*68 + d0+2] + smU[(32+r)*68 + d0+2] + smU[(64+r+1)*68 + d0+2];
        float o3 = cbv*sv.w + smU[(r-1)*68 + d0+3] + smU[(32+r)*68 + d0+3] + smU[(64+r+1)*68 + d0+3];
        pk.hh[0]=f2bf(o0); pk.hh[1]=f2bf(o1); pk.hh[2]=f2bf(o2); pk.hh[3]=f2bf(o3);
        *reinterpret_cast<ushort4*>(&midb[((size_t)b*N_ + n)*C_ + h*D_ + d0]) = pk.u;
      }
    }
  }
}

extern "C" void kernel_launch(void* const* d_in, const int* in_sizes, int n_in,
                              void* d_out, int out_size, void* d_ws, size_t ws_size,
                              hipStream_t stream) {
  const float* x     = (const float*)d_in[0];
  const float* ctx   = (const float*)d_in[1];
  const float* Wq    = (const float*)d_in[2];
  const float* Wkv   = (const float*)d_in[3];
  const float* convw = (const float*)d_in[4];
  const float* convb = (const float*)d_in[5];
  const float* Wp    = (const float*)d_in[6];
  const float* bp    = (const float*)d_in[7];
  float* out = (float*)d_out;

  char* ws = (char*)d_ws;
  bf16* buf0 = (bf16*)(ws);                  // 12582912 B (xb -> ctxb -> midb)
  bf16* Wqt  = (bf16*)(ws + 12582912);       // 1179648
  bf16* Wkvt = (bf16*)(ws + 13762560);       // 2359296
  bf16* Wpt  = (bf16*)(ws + 16121856);       // 1179648
  bf16* Qb   = (bf16*)(ws + 17301504);       // 12582912
  bf16* Kb   = (bf16*)(ws + 29884416);       // 12582912 (frag-tiled)
  bf16* Vt   = (bf16*)(ws + 42467328);       // 12582912 (V row-major -> Y2 tiled)
  float* SVb = (float*)(ws + 55050240);      // 24576   -> end 55074816

  // Y0/Y1 scratch in d_out (25.2 MB), fully overwritten by final GEMM
  bf16* Y0 = (bf16*)d_out;
  bf16* Y1 = (bf16*)((char*)d_out + 12582912);

  transpose_w<<<dim3(24,24), 256, 0, stream>>>(Wq,  Wqt,  768, 768);
  transpose_w<<<dim3(48,24), 256, 0, stream>>>(Wkv, Wkvt, 768, 1536);
  transpose_w<<<dim3(24,24), 256, 0, stream>>>(Wp,  Wpt,  768, 768);

  cvt_bf16<<<3072, 256, 0, stream>>>(x, buf0, 786432);
  gemm_bf16<<<384, 256, 0, stream>>>(buf0, Wqt, 768, 6, nullptr, nullptr, Qb, nullptr, nullptr, 0);
  cvt_bf16<<<3072, 256, 0, stream>>>(ctx, buf0, 786432);
  gemm_bf16<<<768, 256, 0, stream>>>(buf0, Wkvt, 768, 12, nullptr, nullptr, nullptr, Kb, Vt, 1);

  yprep<<<96, 1024, 0, stream>>>(Vt, Y0, Y1, SVb, convw);

  attn_fused<<<dim3(NT,96), dim3(512), 0, stream>>>(Qb, Kb, Y0, Y1, Vt, SVb, convb, buf0);

  gemm_bf16<<<384, 256, 0, stream>>>(buf0, Wpt, 768, 6, bp, out, nullptr, nullptr, nullptr, 2);
}